// Round 5
// baseline (19164.417 us; speedup 1.0000x reference)
//
#include <hip/hip_runtime.h>
#include <hip/hip_bf16.h>
#include <stdint.h>

// Decoder: teacher-forced LSTM + Bahdanau attention, B=256, Tin=512, 255 steps, U=256, V=6.
// R5 = R4 with workspace-layout fix: swz needs 131072 B (65536 x u16); R4 reserved 65536 B
// so k_wmswz clobbered Wfh/Wfc (written earlier by k_wfhc) -> garbage logits projection.
// Barrier-free: one block per batch element owns the whole 255-step recurrence.

typedef unsigned short u16;
typedef unsigned int u32;
typedef short s16x8 __attribute__((ext_vector_type(8)));
typedef float f32x4 __attribute__((ext_vector_type(4)));

#define L2E 1.4426950408889634f

__device__ __forceinline__ u16 f2bf(float f) {
  u32 u = __float_as_uint(f);
  u += 0x7fffu + ((u >> 16) & 1u);
  return (u16)(u >> 16);
}
__device__ __forceinline__ float bflo(u32 p) { return __uint_as_float(p << 16); }
__device__ __forceinline__ float bfhi(u32 p) { return __uint_as_float(p & 0xffff0000u); }

__device__ __forceinline__ float fast_sigmoid(float x) {
  float e = __builtin_amdgcn_exp2f(-x * L2E);
  return __builtin_amdgcn_rcpf(1.f + e);
}
__device__ __forceinline__ float fast_tanh(float x) {
  float e = __builtin_amdgcn_exp2f(x * (2.f * L2E));
  return fmaf(-2.f, __builtin_amdgcn_rcpf(e + 1.f), 1.f);
}

// ---- workspace layout (bytes); high-water 136065024 (~136.07 MB) ----
static const size_t OFF_KEYS = 0;          // keys_T bf16 [256][256][512]   67108864 B
static const size_t OFF_MEMB = 67108864;   // mem bf16 [256][512][256]      67108864 B
static const size_t OFF_WGPK = 134217728;  // (WhC|W2) packed u32 [256][1024] 1048576 B
static const size_t OFF_WH0  = 135266304;  // Wh packed u32 [128][1024]      524288 B (t=0 only)
static const size_t OFF_WQPK = 135790592;  // Wq packed u32 [128][256]       131072 B
static const size_t OFF_WMS  = 135921664;  // Wm swizzled u16[65536]         131072 B (prepass only)
static const size_t OFF_WFH  = 136052736;  // Wa_h@Wf fp32 [256][6]            6144 B
static const size_t OFF_WFC  = 136058880;  // Wa_c@Wf fp32 [256][6]            6144 B

__global__ __launch_bounds__(256) void k_cast(const float* __restrict__ src, u16* __restrict__ dst) {
  int i = blockIdx.x * 256 + threadIdx.x;
  const float4 f = *(const float4*)(src + (size_t)i * 4);
  ushort4 o;
  o.x = f2bf(f.x); o.y = f2bf(f.y); o.z = f2bf(f.z); o.w = f2bf(f.w);
  *(ushort4*)(dst + (size_t)i * 4) = o;
}

// wgpk[k2][j] = bf16pair(WhC|W2 rows 2k2,2k2+1, col j); wh0pk same for raw Wh (k2<128).
// WhC = Wh + Wa[0:256]@Wi[6:262]; W2 = Wa[256:512]@Wi[6:262].
__global__ __launch_bounds__(256) void k_wg(const float* __restrict__ Wi, const float* __restrict__ Wh,
                                            const float* __restrict__ Wa, u32* __restrict__ wgpk,
                                            u32* __restrict__ wh0pk) {
  int bl = blockIdx.x;             // 1024
  int k2 = bl >> 2, cq = bl & 3;
  int j = cq * 256 + threadIdx.x;
  int off = (k2 < 128) ? 0 : 256;
  int ra0 = (k2 < 128) ? (2 * k2) : (2 * k2 - 256);
  const float* wa0 = Wa + (size_t)(off + ra0) * 256;
  const float* wa1 = wa0 + 256;
  float a0 = 0.f, a1 = 0.f;
#pragma unroll 4
  for (int a = 0; a < 256; ++a) {
    float wi = Wi[(size_t)(6 + a) * 1024 + j];
    a0 = fmaf(wa0[a], wi, a0);
    a1 = fmaf(wa1[a], wi, a1);
  }
  if (k2 < 128) {
    float w0 = Wh[(size_t)(2 * k2) * 1024 + j], w1 = Wh[(size_t)(2 * k2 + 1) * 1024 + j];
    wh0pk[k2 * 1024 + j] = (u32)f2bf(w0) | ((u32)f2bf(w1) << 16);
    a0 += w0; a1 += w1;
  }
  wgpk[k2 * 1024 + j] = (u32)f2bf(a0) | ((u32)f2bf(a1) << 16);
}

__global__ __launch_bounds__(256) void k_wqpk(const float* __restrict__ Wq, u32* __restrict__ wqpk) {
  int u2 = blockIdx.x, q = threadIdx.x;   // 128 blocks
  float w0 = Wq[(size_t)(2 * u2) * 256 + q], w1 = Wq[(size_t)(2 * u2 + 1) * 256 + q];
  wqpk[u2 * 256 + q] = (u32)f2bf(w0) | ((u32)f2bf(w1) << 16);
}

__global__ __launch_bounds__(256) void k_wfhc(const float* __restrict__ Wa, const float* __restrict__ Wf,
                                              float* __restrict__ Wfh, float* __restrict__ Wfc) {
  int half = blockIdx.x, r = threadIdx.x;
  float acc[6] = {0.f, 0.f, 0.f, 0.f, 0.f, 0.f};
  const float* war = Wa + (size_t)(half * 256 + r) * 256;
  for (int a = 0; a < 256; ++a) {
    float w = war[a];
    const float* wfr = Wf + a * 6;
#pragma unroll
    for (int j = 0; j < 6; ++j) acc[j] = fmaf(w, wfr[j], acc[j]);
  }
  float* dst = half ? Wfc : Wfh;
#pragma unroll
  for (int j = 0; j < 6; ++j) dst[r * 6 + j] = acc[j];
}

__global__ __launch_bounds__(256) void k_wmswz(const float* __restrict__ Wm, u16* __restrict__ swz) {
  int g = blockIdx.x * 256 + threadIdx.x;
  int j = g & 7, n = (g >> 3) & 255, q = (g >> 11) & 3, i = g >> 13;
  swz[g] = f2bf(Wm[(32 * i + 8 * q + j) * 256 + n]);
}

__global__ __launch_bounds__(256) void k_keys(const u16* __restrict__ memB, const u16* __restrict__ swz,
                                              u16* __restrict__ keysT) {
  int b = blockIdx.x >> 3, tt = blockIdx.x & 7;
  int w = threadIdx.x >> 6, lane = threadIdx.x & 63;
  int q = lane >> 4, mn = lane & 15;
  int t_load = tt * 64 + w * 16 + mn;
  const u16* arow = memB + ((size_t)b * 512 + t_load) * 256;
  s16x8 afr[8];
#pragma unroll
  for (int i = 0; i < 8; ++i) afr[i] = *(const s16x8*)(arow + 32 * i + 8 * q);
  for (int nt = 0; nt < 16; ++nt) {
    f32x4 acc = {0.f, 0.f, 0.f, 0.f};
#pragma unroll
    for (int i = 0; i < 8; ++i) {
      s16x8 bfr = *(const s16x8*)(swz + ((size_t)((i * 4 + q) * 256) + nt * 16 + mn) * 8);
      acc = __builtin_amdgcn_mfma_f32_16x16x32_bf16(afr[i], bfr, acc, 0, 0, 0);
    }
    int u = nt * 16 + mn;
    int tw = tt * 64 + w * 16 + q * 4;
    ushort4 kv;
    kv.x = f2bf(acc[0]); kv.y = f2bf(acc[1]); kv.z = f2bf(acc[2]); kv.w = f2bf(acc[3]);
    *(ushort4*)(keysT + ((size_t)b * 256 + u) * 512 + tw) = kv;
  }
}

__global__ __launch_bounds__(1024) void k_main(
    const int* __restrict__ ids, const float* __restrict__ ench, const float* __restrict__ encc,
    const float* __restrict__ Wi, const float* __restrict__ bvec, const float* __restrict__ vin,
    const float* __restrict__ bfv, const u32* __restrict__ wgpk, const u32* __restrict__ wh0pk,
    const u32* __restrict__ wqpk, const u16* __restrict__ keysT, const u16* __restrict__ memB,
    const float* __restrict__ Wfh, const float* __restrict__ Wfc, float* __restrict__ out) {
  __shared__ float Wx[6][1024];
  __shared__ float bzs[1024];
  __shared__ float wfs[1536];   // Wfh [256][6]
  __shared__ float wcs[1536];   // Wfc [256][6]
  __shared__ float vsh[256];
  __shared__ float bfs[6];
  __shared__ int idss[256];
  __shared__ float hsh[256];
  __shared__ float ctxsh[256];
  __shared__ __align__(16) u32 actpk[256];  // bf16 pairs: [0:128) h, [128:256) ctx
  __shared__ float zsh[1024];
  __shared__ float2 pqv[256];
  __shared__ float qpart[4][256];
  __shared__ float spart[4][512];
  __shared__ float alig[512];
  __shared__ float cpart[8][256];
  __shared__ float red[16];

  const int tid = threadIdx.x;
  const int b = blockIdx.x;

  // ---- prologue: preload all per-step constants into LDS ----
#pragma unroll
  for (int i = 0; i < 6; ++i) Wx[i][tid] = Wi[(size_t)i * 1024 + tid];
  bzs[tid] = bvec[tid];
  for (int i = tid; i < 1536; i += 1024) wfs[i] = Wfh[i];
  for (int i = tid; i < 1536; i += 1024) wcs[i] = Wfc[i];
  if (tid < 6) bfs[tid] = bfv[tid];
  if (tid < 256) {
    vsh[tid] = vin[tid];
    idss[tid] = ids[(size_t)b * 256 + tid];
    hsh[tid] = ench[(size_t)b * 256 + tid];
    ctxsh[tid] = 0.f;
  }
  float creg = (tid < 256) ? encc[(size_t)b * 256 + tid] : 0.f;
  __syncthreads();
  if (tid < 128) actpk[tid] = (u32)f2bf(hsh[2 * tid]) | ((u32)f2bf(hsh[2 * tid + 1]) << 16);
  else if (tid < 256) actpk[tid] = 0u;
  __syncthreads();

  for (int t = 0; t < 255; ++t) {
    // ===== 1. gates: z[j] = acts @ (WhC|W2) + Wi_x[xid] + b =====
    {
      float za0 = 0.f, za1 = 0.f;
      if (t == 0) {
        const u32* wp = wh0pk + tid;
        for (int c = 0; c < 8; ++c) {  // 8 chunks x 16 pairs = 128 pairs (h only)
          uint4 av[4];
#pragma unroll
          for (int q = 0; q < 4; ++q) av[q] = *(const uint4*)&actpk[c * 16 + q * 4];
          u32 w[16];
#pragma unroll
          for (int kk = 0; kk < 16; ++kk) w[kk] = wp[(c * 16 + kk) << 10];
#pragma unroll
          for (int kk = 0; kk < 16; ++kk) {
            u32 a = ((const u32*)av)[kk];
            za0 = fmaf(bflo(w[kk]), bflo(a), za0);
            za1 = fmaf(bfhi(w[kk]), bfhi(a), za1);
          }
        }
      } else {
        const u32* wp = wgpk + tid;
        for (int c = 0; c < 16; ++c) {  // 16 chunks x 16 pairs = 256 pairs (h|ctx)
          uint4 av[4];
#pragma unroll
          for (int q = 0; q < 4; ++q) av[q] = *(const uint4*)&actpk[c * 16 + q * 4];
          u32 w[16];
#pragma unroll
          for (int kk = 0; kk < 16; ++kk) w[kk] = wp[(c * 16 + kk) << 10];
#pragma unroll
          for (int kk = 0; kk < 16; ++kk) {
            u32 a = ((const u32*)av)[kk];
            za0 = fmaf(bflo(w[kk]), bflo(a), za0);
            za1 = fmaf(bfhi(w[kk]), bfhi(a), za1);
          }
        }
      }
      const int xid = idss[t];
      zsh[tid] = za0 + za1 + Wx[xid][tid] + bzs[tid];
    }
    __syncthreads();
    // ===== 2. LSTM pointwise =====
    if (tid < 256) {
      float zi = zsh[tid], zf = zsh[256 + tid], zg = zsh[512 + tid], zo = zsh[768 + tid];
      float gi = fast_sigmoid(zi), gf = fast_sigmoid(zf), go = fast_sigmoid(zo);
      creg = gf * creg + gi * fast_tanh(zg);
      float hn = go * fast_tanh(creg);
      hsh[tid] = hn;
      u32 hb16 = f2bf(hn);
      u32 oth = (u32)__shfl_xor((int)hb16, 1);
      if (!(tid & 1)) actpk[tid >> 1] = hb16 | (oth << 16);
    }
    __syncthreads();
    // ===== 3. pq = h @ Wq =====
    {
      const int quarter = tid >> 8, q = tid & 255;
      const u32* wqp = wqpk + quarter * 32 * 256 + q;
      float p0 = 0.f, p1 = 0.f;
#pragma unroll
      for (int k2 = 0; k2 < 32; ++k2) {
        u32 w = wqp[k2 << 8];
        u32 a = actpk[quarter * 32 + k2];
        p0 = fmaf(bflo(w), bflo(a), p0);
        p1 = fmaf(bfhi(w), bfhi(a), p1);
      }
      qpart[quarter][q] = p0 + p1;
    }
    __syncthreads();
    if (tid < 256) {
      float pq = qpart[0][tid] + qpart[1][tid] + qpart[2][tid] + qpart[3][tid];
      pqv[tid] = make_float2(pq * (2.f * L2E), vsh[tid]);
    }
    __syncthreads();
    // ===== 4. score[t'] = sum_u tanh(keys+pq)*v =====
    {
      const int ug = tid >> 8, tq = tid & 255;
      float s0 = 0.f, s1 = 0.f;
      const u16* kbase = keysT + (size_t)b * 131072 + 2 * tq;
#pragma unroll 8
      for (int u = ug * 64; u < ug * 64 + 64; ++u) {
        u32 kk = __builtin_nontemporal_load((const u32*)(kbase + (size_t)u * 512));
        float2 pv = pqv[u];
        float a0 = fmaf(bflo(kk), 2.f * L2E, pv.x);
        float a1 = fmaf(bfhi(kk), 2.f * L2E, pv.x);
        float r0 = __builtin_amdgcn_rcpf(__builtin_amdgcn_exp2f(a0) + 1.f);
        float r1 = __builtin_amdgcn_rcpf(__builtin_amdgcn_exp2f(a1) + 1.f);
        s0 = fmaf(fmaf(-2.f, r0, 1.f), pv.y, s0);
        s1 = fmaf(fmaf(-2.f, r1, 1.f), pv.y, s1);
      }
      spart[ug][2 * tq] = s0;
      spart[ug][2 * tq + 1] = s1;
    }
    __syncthreads();
    // ===== 5. softmax over 512 =====
    {
      float sc = 0.f, e = 0.f;
      if (tid < 512) {
        sc = spart[0][tid] + spart[1][tid] + spart[2][tid] + spart[3][tid];
        float mx = sc;
#pragma unroll
        for (int o = 32; o >= 1; o >>= 1) mx = fmaxf(mx, __shfl_xor(mx, o));
        if ((tid & 63) == 0) red[tid >> 6] = mx;
      }
      __syncthreads();
      if (tid < 512) {
        float M = red[0];
#pragma unroll
        for (int k = 1; k < 8; ++k) M = fmaxf(M, red[k]);
        e = __builtin_amdgcn_exp2f((sc - M) * L2E);
        float ss = e;
#pragma unroll
        for (int o = 32; o >= 1; o >>= 1) ss += __shfl_xor(ss, o);
        if ((tid & 63) == 0) red[8 + (tid >> 6)] = ss;
      }
      __syncthreads();
      if (tid < 512) {
        float S = 0.f;
#pragma unroll
        for (int k = 0; k < 8; ++k) S += red[8 + k];
        alig[tid] = e * __builtin_amdgcn_rcpf(S);
      }
    }
    __syncthreads();
    // ===== 6. ctx = align @ mem =====
    {
      const int tg = tid >> 7, up = (tid & 127) * 2;
      float c0 = 0.f, c1 = 0.f;
      const u16* mbase = memB + (size_t)b * 131072 + (size_t)tg * 16384 + up;
#pragma unroll 8
      for (int i = 0; i < 64; ++i) {
        u32 mm = __builtin_nontemporal_load((const u32*)(mbase + (size_t)i * 256));
        float al = alig[tg * 64 + i];
        c0 = fmaf(al, bflo(mm), c0);
        c1 = fmaf(al, bfhi(mm), c1);
      }
      cpart[tg][up] = c0;
      cpart[tg][up + 1] = c1;
    }
    __syncthreads();
    if (tid < 256) {
      float cv = 0.f;
#pragma unroll
      for (int k = 0; k < 8; ++k) cv += cpart[k][tid];
      ctxsh[tid] = cv;
      u32 cb16 = f2bf(cv);
      u32 oth = (u32)__shfl_xor((int)cb16, 1);
      if (!(tid & 1)) actpk[128 + (tid >> 1)] = cb16 | (oth << 16);
    }
    __syncthreads();
    // ===== 7. logits = h@Wfh + ctx@Wfc + bf =====
    if (tid < 384) {
      const int jj = tid >> 6, l = tid & 63;
      float acc2 = 0.f;
#pragma unroll
      for (int u = l; u < 256; u += 64)
        acc2 += hsh[u] * wfs[u * 6 + jj] + ctxsh[u] * wcs[u * 6 + jj];
#pragma unroll
      for (int o = 32; o >= 1; o >>= 1) acc2 += __shfl_down(acc2, o);
      if (l == 0) out[((size_t)b * 255 + t) * 6 + jj] = acc2 + bfs[jj];
    }
    __syncthreads();
  }
}

extern "C" void kernel_launch(void* const* d_in, const int* in_sizes, int n_in,
                              void* d_out, int out_size, void* d_ws, size_t ws_size,
                              hipStream_t stream) {
  const int* ids = (const int*)d_in[0];
  const float* mem = (const float*)d_in[1];
  const float* ench = (const float*)d_in[2];
  const float* encc = (const float*)d_in[3];
  const float* Wi = (const float*)d_in[4];
  const float* Wh = (const float*)d_in[5];
  const float* bv = (const float*)d_in[6];
  const float* Wm = (const float*)d_in[7];
  const float* Wq = (const float*)d_in[8];
  const float* vv = (const float*)d_in[9];
  const float* Wa = (const float*)d_in[10];
  const float* Wf = (const float*)d_in[11];
  const float* bf = (const float*)d_in[12];
  float* out = (float*)d_out;

  char* ws = (char*)d_ws;
  u16* keysT = (u16*)(ws + OFF_KEYS);
  u16* memB = (u16*)(ws + OFF_MEMB);
  u32* wgpk = (u32*)(ws + OFF_WGPK);
  u32* wh0pk = (u32*)(ws + OFF_WH0);
  u32* wqpk = (u32*)(ws + OFF_WQPK);
  u16* wms = (u16*)(ws + OFF_WMS);
  float* wfh = (float*)(ws + OFF_WFH);
  float* wfc = (float*)(ws + OFF_WFC);

  hipLaunchKernelGGL(k_cast, dim3(32768), dim3(256), 0, stream, mem, memB);
  hipLaunchKernelGGL(k_wg, dim3(1024), dim3(256), 0, stream, Wi, Wh, Wa, wgpk, wh0pk);
  hipLaunchKernelGGL(k_wqpk, dim3(128), dim3(256), 0, stream, Wq, wqpk);
  hipLaunchKernelGGL(k_wfhc, dim3(2), dim3(256), 0, stream, Wa, Wf, wfh, wfc);
  hipLaunchKernelGGL(k_wmswz, dim3(256), dim3(256), 0, stream, Wm, wms);
  hipLaunchKernelGGL(k_keys, dim3(2048), dim3(256), 0, stream, memB, wms, keysT);
  hipLaunchKernelGGL(k_main, dim3(256), dim3(1024), 0, stream, ids, ench, encc, Wi, bv, vv, bf,
                     wgpk, wh0pk, wqpk, keysT, memB, wfh, wfc, out);
}

// Round 6
// 10325.472 us; speedup vs baseline: 1.8560x; 1.8560x over previous
//
#include <hip/hip_runtime.h>
#include <hip/hip_bf16.h>
#include <stdint.h>

// Decoder: teacher-forced LSTM + Bahdanau attention, B=256, Tin=512, 255 steps, U=256, V=6.
// R6: back to R3's weight-stationary MFMA structure (R5 proved VALU gates + weight
// streaming is worse). New: (1) 16-block GROUP barriers (dependencies are group-local,
// no global convergence), (2) fp8-e4m3 keys+mem (67 MB/step, L3-resident),
// (3) merged score/ctx with M=0 softmax (bounded scores) and no align materialization.

typedef unsigned char u8;
typedef unsigned short u16;
typedef unsigned int u32;
typedef unsigned long long u64;
typedef short s16x8 __attribute__((ext_vector_type(8)));
typedef float f32x4 __attribute__((ext_vector_type(4)));
typedef float f32x2 __attribute__((ext_vector_type(2)));

#define L2E 1.4426950408889634f

__device__ __forceinline__ u16 f2bf(float f) {
  u32 u = __float_as_uint(f);
  u += 0x7fffu + ((u >> 16) & 1u);
  return (u16)(u >> 16);
}
__device__ __forceinline__ float bflo(u32 p) { return __uint_as_float(p << 16); }
__device__ __forceinline__ float bfhi(u32 p) { return __uint_as_float(p & 0xffff0000u); }
__device__ __forceinline__ float b2f(u16 h) { return __uint_as_float(((u32)h) << 16); }

__device__ __forceinline__ float fast_sigmoid(float x) {
  float e = __builtin_amdgcn_exp2f(-x * L2E);
  return __builtin_amdgcn_rcpf(1.f + e);
}
__device__ __forceinline__ float fast_tanh(float x) {
  float e = __builtin_amdgcn_exp2f(x * (2.f * L2E));
  return fmaf(-2.f, __builtin_amdgcn_rcpf(e + 1.f), 1.f);
}

// ---- workspace layout (bytes); high-water 136591360 (same tail as proven R3) ----
static const size_t OFF_K8   = 0;          // keys fp8 [256 b][256 u][512 t]   33554432
static const size_t OFF_M8   = 33554432;   // mem fp8 [256 b][512 t][256 u]    33554432
static const size_t OFF_MEMB = 67108864;   // mem bf16 [b][t][u] (keys prepass) 67108864
static const size_t OFF_WHC  = 134217728;  // WhC bf16 [256][1024]
static const size_t OFF_W2   = 134742016;  // W2  bf16 [256][1024]
static const size_t OFF_WHB  = 135266304;  // Wh  bf16 [256][1024] (t=0 only)
static const size_t OFF_WQT  = 135790592;  // Wq^T bf16 [256][256]
static const size_t OFF_WMS  = 135921664;  // Wm swizzled u16[65536]
static const size_t OFF_WFH  = 136052736;  // Wa_h@Wf fp32 [256][6]
static const size_t OFF_WFC  = 136058880;  // Wa_c@Wf fp32 [256][6]
static const size_t OFF_HB   = 136065024;  // h bf16 [2][256][256]
static const size_t OFF_CTX  = 136327168;  // ctx bf16 [2][256][256]
static const size_t OFF_BAR  = 136589312;  // 16 group counters, 128 B apart

// 16-block group barrier: one monotone relaxed counter per group, no fences.
// __syncthreads drains vmcnt(0) per wave before arrival -> stores visible at coherence pt.
__device__ __forceinline__ void grpbar(u32* gc, unsigned target) {
  __syncthreads();
  if (threadIdx.x == 0) {
    __hip_atomic_fetch_add(gc, 1u, __ATOMIC_RELAXED, __HIP_MEMORY_SCOPE_AGENT);
    while (__hip_atomic_load(gc, __ATOMIC_RELAXED, __HIP_MEMORY_SCOPE_AGENT) < target) {
      __builtin_amdgcn_s_sleep(1);
    }
  }
  __syncthreads();
}

// memory fp32 -> bf16 [b][t][u] AND fp8 [b][t][u]
__global__ __launch_bounds__(256) void k_cast(const float* __restrict__ src, u16* __restrict__ dstb,
                                              u32* __restrict__ dst8) {
  int i = blockIdx.x * 256 + threadIdx.x;
  const float4 f = *(const float4*)(src + (size_t)i * 4);
  ushort4 o;
  o.x = f2bf(f.x); o.y = f2bf(f.y); o.z = f2bf(f.z); o.w = f2bf(f.w);
  *(ushort4*)(dstb + (size_t)i * 4) = o;
  int p8 = __builtin_amdgcn_cvt_pk_fp8_f32(f.x, f.y, 0, false);
  p8 = __builtin_amdgcn_cvt_pk_fp8_f32(f.z, f.w, p8, true);
  dst8[i] = (u32)p8;
}

// WhC = Wh + Wa[0:256]@Wi[6:262];  W2 = Wa[256:512]@Wi[6:262];  also Wh->bf16
__global__ __launch_bounds__(256) void k_whc(const float* __restrict__ Wi, const float* __restrict__ Wh,
                                             const float* __restrict__ Wa, u16* __restrict__ WhCb,
                                             u16* __restrict__ W2b, u16* __restrict__ Whb) {
  int bl = blockIdx.x;
  int half = bl >> 10, r = (bl >> 2) & 255, cq = bl & 3;
  int c = cq * 256 + threadIdx.x;
  const float* war = Wa + (size_t)(half * 256 + r) * 256;
  float acc = 0.f;
#pragma unroll 4
  for (int a = 0; a < 256; ++a) acc = fmaf(war[a], Wi[(size_t)(6 + a) * 1024 + c], acc);
  if (half == 0) {
    float wh = Wh[(size_t)r * 1024 + c];
    WhCb[(size_t)r * 1024 + c] = f2bf(acc + wh);
    Whb[(size_t)r * 1024 + c] = f2bf(wh);
  } else {
    W2b[(size_t)r * 1024 + c] = f2bf(acc);
  }
}

__global__ __launch_bounds__(256) void k_wfhc(const float* __restrict__ Wa, const float* __restrict__ Wf,
                                              float* __restrict__ Wfh, float* __restrict__ Wfc) {
  int half = blockIdx.x, r = threadIdx.x;
  float acc[6] = {0.f, 0.f, 0.f, 0.f, 0.f, 0.f};
  const float* war = Wa + (size_t)(half * 256 + r) * 256;
  for (int a = 0; a < 256; ++a) {
    float w = war[a];
    const float* wfr = Wf + a * 6;
#pragma unroll
    for (int j = 0; j < 6; ++j) acc[j] = fmaf(w, wfr[j], acc[j]);
  }
  float* dst = half ? Wfc : Wfh;
#pragma unroll
  for (int j = 0; j < 6; ++j) dst[r * 6 + j] = acc[j];
}

__global__ __launch_bounds__(256) void k_wqt(const float* __restrict__ Wq, u16* __restrict__ WqT) {
  int g = blockIdx.x * 256 + threadIdx.x;
  int q = g >> 8, u = g & 255;
  WqT[q * 256 + u] = f2bf(Wq[u * 256 + q]);
}

__global__ __launch_bounds__(256) void k_wmswz(const float* __restrict__ Wm, u16* __restrict__ swz) {
  int g = blockIdx.x * 256 + threadIdx.x;
  int j = g & 7, n = (g >> 3) & 255, q = (g >> 11) & 3, i = g >> 13;
  swz[g] = f2bf(Wm[(32 * i + 8 * q + j) * 256 + n]);
}

__global__ __launch_bounds__(256) void k_init(const float* __restrict__ ench, u16* __restrict__ hbuf,
                                              u16* __restrict__ ctxbuf, u32* __restrict__ bar) {
  int b = blockIdx.x, tid = threadIdx.x;
  if (b == 256) {
    for (int i = tid; i < 512; i += 256) bar[i] = 0u;
    return;
  }
  hbuf[b * 256 + tid] = f2bf(ench[b * 256 + tid]);
  ctxbuf[b * 256 + tid] = 0;
}

// keys = mem @ Wm -> fp8 e4m3, TRANSPOSED keys8[b][u][t]
__global__ __launch_bounds__(256) void k_keys(const u16* __restrict__ memB, const u16* __restrict__ swz,
                                              u32* __restrict__ keys8) {
  int b = blockIdx.x >> 3, tt = blockIdx.x & 7;
  int w = threadIdx.x >> 6, lane = threadIdx.x & 63;
  int q = lane >> 4, mn = lane & 15;
  int t_load = tt * 64 + w * 16 + mn;
  const u16* arow = memB + ((size_t)b * 512 + t_load) * 256;
  s16x8 afr[8];
#pragma unroll
  for (int i = 0; i < 8; ++i) afr[i] = *(const s16x8*)(arow + 32 * i + 8 * q);
  for (int nt = 0; nt < 16; ++nt) {
    f32x4 acc = {0.f, 0.f, 0.f, 0.f};
#pragma unroll
    for (int i = 0; i < 8; ++i) {
      s16x8 bfr = *(const s16x8*)(swz + ((size_t)((i * 4 + q) * 256) + nt * 16 + mn) * 8);
      acc = __builtin_amdgcn_mfma_f32_16x16x32_bf16(afr[i], bfr, acc, 0, 0, 0);
    }
    int u = nt * 16 + mn;
    int tw = tt * 64 + w * 16 + q * 4;
    int p8 = __builtin_amdgcn_cvt_pk_fp8_f32(acc[0], acc[1], 0, false);
    p8 = __builtin_amdgcn_cvt_pk_fp8_f32(acc[2], acc[3], p8, true);
    keys8[((size_t)b * 256 + u) * 128 + (tw >> 2)] = (u32)p8;
  }
}

struct ZScratch {
  u16 acts[16][520];        // [b][k]: k<256 h, k>=256 ctx; pitch 520
  float z4p[4][4][16][16];  // [kchunk][gate][row][col] partials
};
struct AScratch {
  float h[256];
  f32x2 pqv[256];           // {pq*2L2E, v}
  float qpart[4][256];
  float spart[8][512];      // score partials, 8 u-groups
  float esh[512];           // exp(score) (M=0)
  float cpart[16][256];     // unnormalized ctx partials, 16 t-groups
  float ctx[256];
  float red[8];
};

__global__ __launch_bounds__(1024) void k_main(
    const int* __restrict__ ids, const float* __restrict__ encc, const float* __restrict__ Wi,
    const float* __restrict__ bvec, const float* __restrict__ vin, const float* __restrict__ bfv,
    const u16* __restrict__ WhCb, const u16* __restrict__ W2b, const u16* __restrict__ Whb,
    const u16* __restrict__ WqT, const u8* __restrict__ keys8, const u8* __restrict__ mem8,
    const float* __restrict__ Wfh, const float* __restrict__ Wfc, u16* __restrict__ hbuf,
    u16* __restrict__ ctxbuf, u32* __restrict__ bar, float* __restrict__ out) {
  __shared__ __align__(16) union { ZScratch z; AScratch a; } smu;
  __shared__ __align__(16) u16 Wz[4][8192];
  __shared__ float Wx[6][64];
  __shared__ float bz[64];
  __shared__ float vsh[256];

  const int tid = threadIdx.x;
  const int bi = blockIdx.x >> 4, uj = blockIdx.x & 15;
  const int bb = blockIdx.x;
  u32* gc = bar + ((bb >> 4) << 5);

  // ---- startup ----
  if (tid < 256) vsh[tid] = vin[tid];
  if (tid < 384) {
    int id = tid >> 6, cl = tid & 63;
    Wx[id][cl] = Wi[(size_t)id * 1024 + 256 * (cl >> 4) + uj * 16 + (cl & 15)];
  }
  if (tid < 64) bz[tid] = bvec[256 * (tid >> 4) + uj * 16 + (tid & 15)];
  for (int ii = tid; ii < 32768; ii += 1024) {
    int g = ii >> 13, x2 = ii & 8191;
    int j = x2 & 7, n = (x2 >> 3) & 15, q2 = (x2 >> 7) & 3, i2 = x2 >> 9;
    int k = 32 * i2 + 8 * q2 + j;
    int col = 256 * g + uj * 16 + n;
    Wz[g][((i2 * 4 + q2) * 16 + n) * 8 + j] =
        (k < 256) ? Whb[(size_t)k * 1024 + col] : W2b[(size_t)(k - 256) * 1024 + col];
  }
  float creg = 0.f;
  if (tid < 256) creg = encc[(size_t)(bi * 16 + (tid >> 4)) * 256 + uj * 16 + (tid & 15)];
  unsigned ep = 0;
  __syncthreads();

  for (int t = 0; t < 255; ++t) {
    const int p = t & 1, p2 = p ^ 1;
    // ================= phase Z (group-local inputs) =================
    {
      const u16* hsrc = hbuf + p * 65536 + bi * 4096;
      const u16* csrc = ctxbuf + p * 65536 + bi * 4096;
#pragma unroll
      for (int k2 = 0; k2 < 2; ++k2) {
        int gidx = tid + k2 * 1024;
        int half = gidx >> 10, idx = gidx & 1023;
        int r = idx >> 6, c = idx & 63;
        const u16* srcp = (half ? csrc : hsrc) + r * 256 + c * 4;
        u64 val = __hip_atomic_load((const u64*)srcp, __ATOMIC_RELAXED, __HIP_MEMORY_SCOPE_AGENT);
        *(u64*)(&smu.z.acts[r][half * 256 + c * 4]) = val;
      }
      __syncthreads();
      {
        const int w = tid >> 6, lane = tid & 63, q = lane >> 4, mn = lane & 15;
        const int g = w & 3, kc = w >> 2;
        f32x4 acc = {0.f, 0.f, 0.f, 0.f};
#pragma unroll
        for (int ii2 = 0; ii2 < 4; ++ii2) {
          int i = kc * 4 + ii2;
          s16x8 af = *(const s16x8*)(&smu.z.acts[mn][32 * i + 8 * q]);
          s16x8 bvf = *(const s16x8*)(&Wz[g][((i * 4 + q) * 16 + mn) * 8]);
          acc = __builtin_amdgcn_mfma_f32_16x16x32_bf16(af, bvf, acc, 0, 0, 0);
        }
#pragma unroll
        for (int r2 = 0; r2 < 4; ++r2) smu.z.z4p[kc][g][q * 4 + r2][mn] = acc[r2];
      }
      __syncthreads();
      if (tid < 256) {
        const int b_l = tid >> 4, u_l = tid & 15;
        const int b_g = bi * 16 + b_l, u_g = uj * 16 + u_l;
        const int xid = ids[b_g * 256 + t];
        float zi = smu.z.z4p[0][0][b_l][u_l] + smu.z.z4p[1][0][b_l][u_l] +
                   smu.z.z4p[2][0][b_l][u_l] + smu.z.z4p[3][0][b_l][u_l] + Wx[xid][u_l] + bz[u_l];
        float zf = smu.z.z4p[0][1][b_l][u_l] + smu.z.z4p[1][1][b_l][u_l] +
                   smu.z.z4p[2][1][b_l][u_l] + smu.z.z4p[3][1][b_l][u_l] + Wx[xid][16 + u_l] + bz[16 + u_l];
        float zg = smu.z.z4p[0][2][b_l][u_l] + smu.z.z4p[1][2][b_l][u_l] +
                   smu.z.z4p[2][2][b_l][u_l] + smu.z.z4p[3][2][b_l][u_l] + Wx[xid][32 + u_l] + bz[32 + u_l];
        float zo = smu.z.z4p[0][3][b_l][u_l] + smu.z.z4p[1][3][b_l][u_l] +
                   smu.z.z4p[2][3][b_l][u_l] + smu.z.z4p[3][3][b_l][u_l] + Wx[xid][48 + u_l] + bz[48 + u_l];
        float gi = fast_sigmoid(zi), gf = fast_sigmoid(zf), go = fast_sigmoid(zo);
        creg = gf * creg + gi * fast_tanh(zg);
        float hn = go * fast_tanh(creg);
        u32 hb16 = f2bf(hn);
        u32 other = (u32)__shfl_xor((int)hb16, 1);
        if ((tid & 1) == 0) {
          __hip_atomic_store((u32*)(hbuf + p2 * 65536 + b_g * 256 + u_g), hb16 | (other << 16),
                             __ATOMIC_RELAXED, __HIP_MEMORY_SCOPE_AGENT);
        }
      }
      if (t == 0) {  // swap Wh -> WhC for steps >= 1
        for (int ii3 = tid; ii3 < 16384; ii3 += 1024) {
          int g = ii3 >> 12, x2 = ii3 & 4095;
          int j = x2 & 7, n = (x2 >> 3) & 15, q2 = (x2 >> 7) & 3, i2 = (x2 >> 9) & 7;
          int k = 32 * i2 + 8 * q2 + j;
          Wz[g][((i2 * 4 + q2) * 16 + n) * 8 + j] = WhCb[(size_t)k * 1024 + 256 * g + uj * 16 + n];
        }
      }
    }
    grpbar(gc, (++ep) << 4);
    // ================= phase A (block bb = batch; fp8 keys/mem; M=0 softmax) =========
    {
      if (tid < 64) {
        const u16* hp = hbuf + p2 * 65536 + bb * 256 + tid * 4;
        u64 hv = __hip_atomic_load((const u64*)hp, __ATOMIC_RELAXED, __HIP_MEMORY_SCOPE_AGENT);
        smu.a.h[tid * 4 + 0] = b2f((u16)(hv));
        smu.a.h[tid * 4 + 1] = b2f((u16)(hv >> 16));
        smu.a.h[tid * 4 + 2] = b2f((u16)(hv >> 32));
        smu.a.h[tid * 4 + 3] = b2f((u16)(hv >> 48));
      }
      __syncthreads();
      {  // pq partials: 4 quarters x 256 q
        const int quarter = tid >> 8, qq = tid & 255;
        const u16* wqrow = WqT + qq * 256 + quarter * 64;
        const float* hq = &smu.a.h[quarter * 64];
        float pq = 0.f;
#pragma unroll
        for (int j = 0; j < 8; ++j) {
          uint4 wv = *(const uint4*)(wqrow + j * 8);
          pq = fmaf(bflo(wv.x), hq[j * 8 + 0], pq);
          pq = fmaf(bfhi(wv.x), hq[j * 8 + 1], pq);
          pq = fmaf(bflo(wv.y), hq[j * 8 + 2], pq);
          pq = fmaf(bfhi(wv.y), hq[j * 8 + 3], pq);
          pq = fmaf(bflo(wv.z), hq[j * 8 + 4], pq);
          pq = fmaf(bfhi(wv.z), hq[j * 8 + 5], pq);
          pq = fmaf(bflo(wv.w), hq[j * 8 + 6], pq);
          pq = fmaf(bfhi(wv.w), hq[j * 8 + 7], pq);
        }
        smu.a.qpart[quarter][qq] = pq;
      }
      __syncthreads();
      if (tid < 256) {
        float pq = smu.a.qpart[0][tid] + smu.a.qpart[1][tid] + smu.a.qpart[2][tid] + smu.a.qpart[3][tid];
        f32x2 pv; pv.x = pq * (2.f * L2E); pv.y = vsh[tid];
        smu.a.pqv[tid] = pv;
      }
      __syncthreads();
      {  // score partials: 8 u-groups (32 u) x 128 threads (4 t each), fp8 keys
        const int ug = tid >> 7, tq = tid & 127;
        float s0 = 0.f, s1 = 0.f, s2 = 0.f, s3 = 0.f;
        const u32* kb = (const u32*)(keys8 + (size_t)bb * 131072) + tq;
#pragma unroll 4
        for (int u = ug * 32; u < ug * 32 + 32; ++u) {
          u32 kk = __builtin_nontemporal_load(kb + u * 128);
          f32x2 pv = smu.a.pqv[u];
          f32x2 lo = __builtin_amdgcn_cvt_pk_f32_fp8(kk, false);
          f32x2 hi = __builtin_amdgcn_cvt_pk_f32_fp8(kk, true);
          float a0 = fmaf(lo.x, 2.f * L2E, pv.x);
          float a1 = fmaf(lo.y, 2.f * L2E, pv.x);
          float a2 = fmaf(hi.x, 2.f * L2E, pv.x);
          float a3 = fmaf(hi.y, 2.f * L2E, pv.x);
          float r0 = __builtin_amdgcn_rcpf(__builtin_amdgcn_exp2f(a0) + 1.f);
          float r1 = __builtin_amdgcn_rcpf(__builtin_amdgcn_exp2f(a1) + 1.f);
          float r2 = __builtin_amdgcn_rcpf(__builtin_amdgcn_exp2f(a2) + 1.f);
          float r3 = __builtin_amdgcn_rcpf(__builtin_amdgcn_exp2f(a3) + 1.f);
          s0 = fmaf(fmaf(-2.f, r0, 1.f), pv.y, s0);
          s1 = fmaf(fmaf(-2.f, r1, 1.f), pv.y, s1);
          s2 = fmaf(fmaf(-2.f, r2, 1.f), pv.y, s2);
          s3 = fmaf(fmaf(-2.f, r3, 1.f), pv.y, s3);
        }
        float4 sv; sv.x = s0; sv.y = s1; sv.z = s2; sv.w = s3;
        *(float4*)&smu.a.spart[ug][4 * tq] = sv;
      }
      __syncthreads();
      // e = exp(score) with M=0 (|score| <= ||v||_1 ~ 10, safe in fp32); sum-reduce
      if (tid < 512) {
        float sc = smu.a.spart[0][tid] + smu.a.spart[1][tid] + smu.a.spart[2][tid] +
                   smu.a.spart[3][tid] + smu.a.spart[4][tid] + smu.a.spart[5][tid] +
                   smu.a.spart[6][tid] + smu.a.spart[7][tid];
        float e = __builtin_amdgcn_exp2f(sc * L2E);
        smu.a.esh[tid] = e;
        float ss = e;
#pragma unroll
        for (int o = 32; o >= 1; o >>= 1) ss += __shfl_xor(ss, o);
        if ((tid & 63) == 0) smu.a.red[tid >> 6] = ss;
      }
      __syncthreads();
      {  // unnormalized ctx partials: 16 t-groups (32 t) x 64 threads (4 u each), fp8 mem
        const int tg = tid >> 6, uq = tid & 63;
        float c0 = 0.f, c1 = 0.f, c2 = 0.f, c3 = 0.f;
        const u32* mb = (const u32*)(mem8 + (size_t)bb * 131072) + uq;
#pragma unroll 4
        for (int i = 0; i < 32; ++i) {
          int tt2 = tg * 32 + i;
          u32 mm = __builtin_nontemporal_load(mb + tt2 * 64);
          float e = smu.a.esh[tt2];
          f32x2 lo = __builtin_amdgcn_cvt_pk_f32_fp8(mm, false);
          f32x2 hi = __builtin_amdgcn_cvt_pk_f32_fp8(mm, true);
          c0 = fmaf(e, lo.x, c0);
          c1 = fmaf(e, lo.y, c1);
          c2 = fmaf(e, hi.x, c2);
          c3 = fmaf(e, hi.y, c3);
        }
        float4 cv4; cv4.x = c0; cv4.y = c1; cv4.z = c2; cv4.w = c3;
        *(float4*)&smu.a.cpart[tg][4 * uq] = cv4;
      }
      __syncthreads();
      if (tid < 256) {
        float S = (smu.a.red[0] + smu.a.red[1]) + (smu.a.red[2] + smu.a.red[3]) +
                  (smu.a.red[4] + smu.a.red[5]) + (smu.a.red[6] + smu.a.red[7]);
        float rs = __builtin_amdgcn_rcpf(S);
        float cv = 0.f;
#pragma unroll
        for (int k = 0; k < 16; ++k) cv += smu.a.cpart[k][tid];
        cv *= rs;
        smu.a.ctx[tid] = cv;
        u32 cb16 = f2bf(cv);
        u32 oth = (u32)__shfl_xor((int)cb16, 1);
        if (!(tid & 1)) {
          __hip_atomic_store((u32*)(ctxbuf + p2 * 65536 + bb * 256 + tid), cb16 | (oth << 16),
                             __ATOMIC_RELAXED, __HIP_MEMORY_SCOPE_AGENT);
        }
      }
      __syncthreads();
      if (tid < 384) {  // logits: 6 outputs x one wave each
        const int jj = tid >> 6, l = tid & 63;
        float acc2 = 0.f;
#pragma unroll
        for (int u = l; u < 256; u += 64)
          acc2 += smu.a.h[u] * Wfh[u * 6 + jj] + smu.a.ctx[u] * Wfc[u * 6 + jj];
#pragma unroll
        for (int o = 32; o >= 1; o >>= 1) acc2 += __shfl_down(acc2, o);
        if (l == 0) out[((size_t)bb * 255 + t) * 6 + jj] = acc2 + bfv[jj];
      }
    }
    grpbar(gc, (++ep) << 4);
  }
}

extern "C" void kernel_launch(void* const* d_in, const int* in_sizes, int n_in,
                              void* d_out, int out_size, void* d_ws, size_t ws_size,
                              hipStream_t stream) {
  const int* ids = (const int*)d_in[0];
  const float* mem = (const float*)d_in[1];
  const float* ench = (const float*)d_in[2];
  const float* encc = (const float*)d_in[3];
  const float* Wi = (const float*)d_in[4];
  const float* Wh = (const float*)d_in[5];
  const float* bv = (const float*)d_in[6];
  const float* Wm = (const float*)d_in[7];
  const float* Wq = (const float*)d_in[8];
  const float* vv = (const float*)d_in[9];
  const float* Wa = (const float*)d_in[10];
  const float* Wf = (const float*)d_in[11];
  const float* bf = (const float*)d_in[12];
  float* out = (float*)d_out;

  char* ws = (char*)d_ws;
  u8* keys8 = (u8*)(ws + OFF_K8);
  u8* mem8 = (u8*)(ws + OFF_M8);
  u16* memB = (u16*)(ws + OFF_MEMB);
  u16* whcb = (u16*)(ws + OFF_WHC);
  u16* w2b = (u16*)(ws + OFF_W2);
  u16* whb = (u16*)(ws + OFF_WHB);
  u16* wqt = (u16*)(ws + OFF_WQT);
  u16* wms = (u16*)(ws + OFF_WMS);
  float* wfh = (float*)(ws + OFF_WFH);
  float* wfc = (float*)(ws + OFF_WFC);
  u16* hb = (u16*)(ws + OFF_HB);
  u16* cb = (u16*)(ws + OFF_CTX);
  u32* bar = (u32*)(ws + OFF_BAR);

  hipLaunchKernelGGL(k_cast, dim3(32768), dim3(256), 0, stream, mem, memB, (u32*)mem8);
  hipLaunchKernelGGL(k_whc, dim3(2048), dim3(256), 0, stream, Wi, Wh, Wa, whcb, w2b, whb);
  hipLaunchKernelGGL(k_wfhc, dim3(2), dim3(256), 0, stream, Wa, Wf, wfh, wfc);
  hipLaunchKernelGGL(k_wqt, dim3(256), dim3(256), 0, stream, Wq, wqt);
  hipLaunchKernelGGL(k_wmswz, dim3(256), dim3(256), 0, stream, Wm, wms);
  hipLaunchKernelGGL(k_init, dim3(257), dim3(256), 0, stream, ench, hb, cb, bar);
  hipLaunchKernelGGL(k_keys, dim3(2048), dim3(256), 0, stream, memB, wms, (u32*)keys8);
  hipLaunchKernelGGL(k_main, dim3(256), dim3(1024), 0, stream, ids, encc, Wi, bv, vv, bf,
                     whcb, w2b, whb, wqt, keys8, mem8, wfh, wfc, hb, cb, bar, out);
}